// Round 8
// baseline (551.534 us; speedup 1.0000x reference)
//
#include <hip/hip_runtime.h>
#include <hip/hip_bf16.h>

typedef __attribute__((ext_vector_type(8))) short bf16x8;
typedef __attribute__((ext_vector_type(4))) float f32x4;
typedef __attribute__((ext_vector_type(4))) unsigned int u32x4;
typedef unsigned long long ull;

#define RT 128
#define NB (262144 / RT)
#define XSTR 40   // x row stride in bf16 elems (aug pair at 24/25, zeros 26..31)

// LDS byte offsets
#define X_OFF 0          // x: [4][128][XSTR] bf16  = 40960 B
#define O_OFF 40960      // o: [4][2][129][12] bf16 = 24768 B
#define Y_OFF 65728      // y: [2][128][12] bf16    =  6144 B
#define E_OFF 71872      // e: [128] f32            =   512 B
#define SMEM_BYTES 72384

// 3-VALU bf16 pair pack (round-6-verified; NO inline asm — asm cvt_pk proven
// poison in r5): ties-away rounding via +0x8000, then v_perm_b32 packs the
// two high halves: D[15:0]=bf16(lo), D[31:16]=bf16(hi).
__device__ __forceinline__ unsigned pk2(float lo, float hi) {
  union { float f; unsigned u; } a, b;
  a.f = lo; b.f = hi;
  return __builtin_amdgcn_perm(b.u + 0x8000u, a.u + 0x8000u, 0x07060302u);
}
__device__ __forceinline__ void unp4(ull v, float* d) {
  unsigned a = (unsigned)v, b = (unsigned)(v >> 32);
  union { unsigned u; float f; } x;
  x.u = a << 16;         d[0] = x.f;
  x.u = a & 0xffff0000u; d[1] = x.f;
  x.u = b << 16;         d[2] = x.f;
  x.u = b & 0xffff0000u; d[3] = x.f;
}
__device__ __forceinline__ bf16x8 mkfrag(unsigned w0, unsigned w1, unsigned w2, unsigned w3) {
  union { bf16x8 v; unsigned u[4]; } U;
  U.u[0] = w0; U.u[1] = w1; U.u[2] = w2; U.u[3] = w3;
  return U.v;
}
__device__ __forceinline__ f32x4 mfma16(bf16x8 a, bf16x8 b, f32x4 c) {
  return __builtin_amdgcn_mfma_f32_16x16x32_bf16(a, b, c, 0, 0, 0);
}

// ROUND-8 = ROUND-7 resubmitted (infra failure, no data): 16x16x32 geometry
// so accumulators are f32x4 (total reg demand ~128 incl AGPR) -> 4 waves/SIMD.
// psi-permutation keeps the inter-layer hop register-contiguous (same
// mechanism as r3's verified phi):
//   psi(16*mt + 4*g + r) = 32*(mt>>1) + 8*g + 4*(mt&1) + r
// Storage feature m' holds actual feature psi(m'); applied to W1/W2 output
// columns and b1/b2. Then B-frag elem j (=4a+r) of k-window kt is exactly
// C-reg c[2kt+a][r] — zero data movement.
__global__ __launch_bounds__(512, 4) void rrsep(
    const float* __restrict__ y_real, const float* __restrict__ y_imag,
    const float* __restrict__ W1, const float* __restrict__ b1,
    const float* __restrict__ W2, const float* __restrict__ b2,
    const float* __restrict__ W3, const float* __restrict__ b3,
    float* __restrict__ out)
{
  __shared__ __align__(16) char smem[SMEM_BYTES];
  unsigned short* xs = (unsigned short*)(smem + X_OFF);
  unsigned short* os = (unsigned short*)(smem + O_OFF);
  unsigned short* ys = (unsigned short*)(smem + Y_OFF);
  float* es = (float*)(smem + E_OFF);

  const int tid  = (int)threadIdx.x;
  const int lane = tid & 63;
  const int w    = tid >> 6;     // wave 0..7
  const int p    = w >> 1;       // port
  const int c    = w & 1;        // channel
  const int q    = lane & 15;    // A/B row-col lane index
  const int g    = lane >> 4;    // k-group / C-row group
  const long r0  = (long)blockIdx.x * RT;

  // psi for A-frag rows (m' = 16mt + q) — stage-invariant
  int mpsi[4];
  #pragma unroll
  for (int mt = 0; mt < 4; ++mt)
    mpsi[mt] = 32*(mt>>1) + 8*(q>>2) + 4*(mt&1) + (q&3);

  // ---------------- prologue: coalesced load, normalize, init x ----------------
  {
    float* stg = (float*)smem;   // overlays x region before its first use
    if (tid < 384) {
      ((f32x4*)stg)[tid]          = ((const f32x4*)(y_real + r0 * 12))[tid];
      ((f32x4*)(stg + 1536))[tid] = ((const f32x4*)(y_imag + r0 * 12))[tid];
    }
    __syncthreads();
    float yv[24]; float ev = 0.f, inv = 0.f;
    if (tid < RT) {
      float acc = 0.f;
      #pragma unroll
      for (int l = 0; l < 12; ++l) {
        yv[l]      = stg[tid * 12 + l];
        yv[12 + l] = stg[1536 + tid * 12 + l];
        acc += yv[l] * yv[l] + yv[12 + l] * yv[12 + l];
      }
      ev  = sqrtf(acc * (1.f / 12.f));
      inv = 1.f / (ev + 1e-8f);
    }
    __syncthreads();   // all slab reads done before x overwrites the region
    if (tid < RT) {
      es[tid] = ev;
      unsigned pkw[12];
      #pragma unroll
      for (int j = 0; j < 12; ++j) pkw[j] = pk2(yv[2*j] * inv, yv[2*j+1] * inv);
      ull* yr0 = (ull*)(ys + (0 * RT + tid) * 12);
      yr0[0] = (ull)pkw[0] | ((ull)pkw[1] << 32);
      yr0[1] = (ull)pkw[2] | ((ull)pkw[3] << 32);
      yr0[2] = (ull)pkw[4] | ((ull)pkw[5] << 32);
      ull* yr1 = (ull*)(ys + (1 * RT + tid) * 12);
      yr1[0] = (ull)pkw[6]  | ((ull)pkw[7]  << 32);
      yr1[1] = (ull)pkw[8]  | ((ull)pkw[9]  << 32);
      yr1[2] = (ull)pkw[10] | ((ull)pkw[11] << 32);
      #pragma unroll
      for (int p2 = 0; p2 < 4; ++p2) {
        u32x4* xr = (u32x4*)(xs + (p2 * RT + tid) * XSTR);
        u32x4 t0; t0[0]=pkw[0]; t0[1]=pkw[1]; t0[2]=pkw[2]; t0[3]=pkw[3];
        u32x4 t1; t1[0]=pkw[4]; t1[1]=pkw[5]; t1[2]=pkw[6]; t1[3]=pkw[7];
        u32x4 t2; t2[0]=pkw[8]; t2[1]=pkw[9]; t2[2]=pkw[10]; t2[3]=pkw[11];
        u32x4 t3; t3[0]=pk2(1.f, 0.f); t3[1]=0u; t3[2]=0u; t3[3]=0u;  // aug x[24]=1, pad 25..31=0
        xr[0]=t0; xr[1]=t1; xr[2]=t2; xr[3]=t3;
      }
    }
    __syncthreads();
  }

  #pragma unroll 1
  for (int s = 0; s < 3; ++s) {
    const int pc = (s * 4 + p) * 2 + c;
    const float* W1g = W1 + pc * 24 * 64;
    const float* b1g = b1 + pc * 64;
    const float* W2g = W2 + pc * 64 * 64;
    const float* b2g = b2 + pc * 64;
    const float* W3g = W3 + pc * 64 * 12;
    const float* b3g = b3 + pc * 12;

    // ---- W1 A-frags (psi on output cols, b1 folded at k=24): elem j <-> k=8g+j ----
    bf16x8 w1f[4];
    #pragma unroll
    for (int mt = 0; mt < 4; ++mt) {
      unsigned u[4];
      #pragma unroll
      for (int wq = 0; wq < 4; ++wq) {
        int k0 = 8*g + 2*wq;
        float v0 = (k0 < 24) ? W1g[k0*64 + mpsi[mt]] : ((k0 == 24) ? b1g[mpsi[mt]] : 0.f);
        float v1 = (k0+1 < 24) ? W1g[(k0+1)*64 + mpsi[mt]] : 0.f;   // k0+1 odd, never 24
        u[wq] = pk2(v0, v1);
      }
      w1f[mt] = mkfrag(u[0], u[1], u[2], u[3]);
    }
    // ---- W2 A-frags (input k actual, psi on output cols): k = 32kt+8g+j ----
    bf16x8 w2f[2][4];
    #pragma unroll
    for (int kt = 0; kt < 2; ++kt)
      #pragma unroll
      for (int mt = 0; mt < 4; ++mt) {
        unsigned u[4];
        #pragma unroll
        for (int wq = 0; wq < 4; ++wq) {
          int k0 = 32*kt + 8*g + 2*wq;
          u[wq] = pk2(W2g[k0*64 + mpsi[mt]], W2g[(k0+1)*64 + mpsi[mt]]);
        }
        w2f[kt][mt] = mkfrag(u[0], u[1], u[2], u[3]);
      }
    // ---- W3 A-frags (all actual; M=12 padded to 16 with zeros) ----
    bf16x8 w3f[2];
    #pragma unroll
    for (int kt = 0; kt < 2; ++kt) {
      unsigned u[4];
      #pragma unroll
      for (int wq = 0; wq < 4; ++wq) {
        int k0 = 32*kt + 8*g + 2*wq;
        float v0 = (q < 12) ? W3g[k0*12 + q]     : 0.f;
        float v1 = (q < 12) ? W3g[(k0+1)*12 + q] : 0.f;
        u[wq] = pk2(v0, v1);
      }
      w3f[kt] = mkfrag(u[0], u[1], u[2], u[3]);
    }
    // ---- biases as C-init (round-1-verified): C row = 4g+reg ----
    f32x4 b2f[4], b3f;
    #pragma unroll
    for (int mt = 0; mt < 4; ++mt) {
      #pragma unroll
      for (int r = 0; r < 4; ++r)
        b2f[mt][r] = b2g[32*(mt>>1) + 8*g + 4*(mt&1) + r];   // b2[psi(16mt+4g+r)]
    }
    #pragma unroll
    for (int r = 0; r < 4; ++r) {
      int m = 4*g + r;
      b3f[r] = (m < 12) ? b3g[m] : 0.f;
    }

    // ---------------- main: 8 chunks of 16 rows, register-resident ----------------
    #pragma unroll 1
    for (int ch = 0; ch < 8; ++ch) {
      const int row = ch * 16 + q;
      bf16x8 xb = *(const bf16x8*)(xs + (p * RT + row) * XSTR + 8 * g);

      // mm1: H1psi^T = W1psi^T · [X|1]^T   (K=32 covers 24 data + aug + pad)
      f32x4 c1[4];
      #pragma unroll
      for (int mt = 0; mt < 4; ++mt) c1[mt] = mfma16(w1f[mt], xb, f32x4{0.f,0.f,0.f,0.f});

      // hop1: relu+pack contiguous C-regs; fr1[kt] elem 4a+r = c1[2kt+a][r]
      bf16x8 fr1[2];
      #pragma unroll
      for (int kt = 0; kt < 2; ++kt)
        fr1[kt] = mkfrag(
          pk2(fmaxf(c1[2*kt][0], 0.f),   fmaxf(c1[2*kt][1], 0.f)),
          pk2(fmaxf(c1[2*kt][2], 0.f),   fmaxf(c1[2*kt][3], 0.f)),
          pk2(fmaxf(c1[2*kt+1][0], 0.f), fmaxf(c1[2*kt+1][1], 0.f)),
          pk2(fmaxf(c1[2*kt+1][2], 0.f), fmaxf(c1[2*kt+1][3], 0.f)));

      // mm2: bias via C-init, K=64 as two k-windows
      f32x4 c2[4];
      #pragma unroll
      for (int mt = 0; mt < 4; ++mt) {
        c2[mt] = mfma16(w2f[0][mt], fr1[0], b2f[mt]);
        c2[mt] = mfma16(w2f[1][mt], fr1[1], c2[mt]);
      }
      // hop2
      bf16x8 fr2[2];
      #pragma unroll
      for (int kt = 0; kt < 2; ++kt)
        fr2[kt] = mkfrag(
          pk2(fmaxf(c2[2*kt][0], 0.f),   fmaxf(c2[2*kt][1], 0.f)),
          pk2(fmaxf(c2[2*kt][2], 0.f),   fmaxf(c2[2*kt][3], 0.f)),
          pk2(fmaxf(c2[2*kt+1][0], 0.f), fmaxf(c2[2*kt+1][1], 0.f)),
          pk2(fmaxf(c2[2*kt+1][2], 0.f), fmaxf(c2[2*kt+1][3], 0.f)));

      // mm3: O^T (12 valid rows), bias via C-init
      f32x4 c3 = mfma16(w3f[0], fr2[0], b3f);
      c3 = mfma16(w3f[1], fr2[1], c3);

      // o-write: C reg r = out-feat 4g+r at data row `row`; g<3 covers feats 0..11
      if (g < 3) {
        unsigned k0 = pk2(c3[0], c3[1]);
        unsigned k1 = pk2(c3[2], c3[3]);
        *(ull*)(os + ((p * 2 + c) * 129 + row) * 12 + 4 * g) = (ull)k0 | ((ull)k1 << 32);
      }
    }
    __syncthreads();

    // ---------------- residual combine (round-3-verified, unchanged) ----------------
    {
      const int r = tid >> 2, pp = tid & 3;
      float sum[24], own[24], yn[24];
      #pragma unroll
      for (int k = 0; k < 24; ++k) sum[k] = 0.f;
      #pragma unroll
      for (int pp2 = 0; pp2 < 4; ++pp2)
        #pragma unroll
        for (int cc = 0; cc < 2; ++cc) {
          const ull* orow = (const ull*)(os + ((pp2 * 2 + cc) * 129 + r) * 12);
          float t[12];
          unp4(orow[0], t); unp4(orow[1], t + 4); unp4(orow[2], t + 8);
          #pragma unroll
          for (int l = 0; l < 12; ++l) sum[cc * 12 + l] += t[l];
        }
      #pragma unroll
      for (int cc = 0; cc < 2; ++cc) {
        const ull* orow = (const ull*)(os + ((pp * 2 + cc) * 129 + r) * 12);
        unp4(orow[0], own + cc * 12); unp4(orow[1], own + cc * 12 + 4); unp4(orow[2], own + cc * 12 + 8);
        const ull* yrow = (const ull*)(ys + (cc * RT + r) * 12);
        unp4(yrow[0], yn + cc * 12); unp4(yrow[1], yn + cc * 12 + 4); unp4(yrow[2], yn + cc * 12 + 8);
      }
      if (s < 2) {
        unsigned xw[12];
        #pragma unroll
        for (int j = 0; j < 12; ++j) {
          float v0 = own[2*j]   + (yn[2*j]   - sum[2*j]);
          float v1 = own[2*j+1] + (yn[2*j+1] - sum[2*j+1]);
          xw[j] = pk2(v0, v1);
        }
        u32x4* xr = (u32x4*)(xs + (pp * RT + r) * XSTR);
        u32x4 t0; t0[0]=xw[0]; t0[1]=xw[1]; t0[2]=xw[2];  t0[3]=xw[3];
        u32x4 t1; t1[0]=xw[4]; t1[1]=xw[5]; t1[2]=xw[6];  t1[3]=xw[7];
        u32x4 t2; t2[0]=xw[8]; t2[1]=xw[9]; t2[2]=xw[10]; t2[3]=xw[11];
        xr[0]=t0; xr[1]=t1; xr[2]=t2;
        __syncthreads();
      } else {
        const float ev = es[r];
        float vals[24];
        #pragma unroll
        for (int l = 0; l < 12; ++l) {
          vals[2*l]   = (own[l]      + yn[l]      - sum[l])      * ev;
          vals[2*l+1] = (own[12 + l] + yn[12 + l] - sum[12 + l]) * ev;
        }
        __syncthreads();                       // all o/y/e reads done
        float* vstg = (float*)smem;            // overlays x/o regions
        f32x4* vw = (f32x4*)(vstg + r * 96 + pp * 24);
        #pragma unroll
        for (int i = 0; i < 6; ++i) {
          f32x4 t; t[0]=vals[4*i]; t[1]=vals[4*i+1]; t[2]=vals[4*i+2]; t[3]=vals[4*i+3];
          vw[i] = t;
        }
        __syncthreads();
        const f32x4* vp = (const f32x4*)vstg;
        f32x4* og = (f32x4*)(out + r0 * 96);
        #pragma unroll
        for (int i = 0; i < 6; ++i) og[tid + 512 * i] = vp[tid + 512 * i];
      }
    }
  }
}

extern "C" void kernel_launch(void* const* d_in, const int* in_sizes, int n_in,
                              void* d_out, int out_size, void* d_ws, size_t ws_size,
                              hipStream_t stream) {
  const float* y_real = (const float*)d_in[0];
  const float* y_imag = (const float*)d_in[1];
  const float* W1 = (const float*)d_in[2];
  const float* b1 = (const float*)d_in[3];
  const float* W2 = (const float*)d_in[4];
  const float* b2 = (const float*)d_in[5];
  const float* W3 = (const float*)d_in[6];
  const float* b3 = (const float*)d_in[7];
  float* out = (float*)d_out;

  hipLaunchKernelGGL(rrsep, dim3(NB), dim3(512), 0, stream,
                     y_real, y_imag, W1, b1, W2, b2, W3, b3, out);
}

// Round 11
// 299.149 us; speedup vs baseline: 1.8437x; 1.8437x over previous
//
#include <hip/hip_runtime.h>
#include <hip/hip_bf16.h>

typedef __attribute__((ext_vector_type(8))) short bf16x8;
typedef __attribute__((ext_vector_type(4))) float f32x4;
typedef __attribute__((ext_vector_type(4))) unsigned int u32x4;
typedef unsigned long long ull;

#define RT 128
#define NB (262144 / RT)
#define XSTR 40   // x row stride in bf16 elems (aug pair at 24/25, zeros 26..31)

// LDS byte offsets
#define X_OFF 0          // x: [4][128][XSTR] bf16  = 40960 B
#define O_OFF 40960      // o: [4][2][129][12] bf16 = 24768 B
#define Y_OFF 65728      // y: [2][128][12] bf16    =  6144 B
#define E_OFF 71872      // e: [128] f32            =   512 B
#define SMEM_BYTES 72384

// 3-VALU bf16 pair pack (round-6-verified; NO inline asm — asm cvt_pk proven
// poison in r5): ties-away rounding via +0x8000, then v_perm_b32 packs the
// two high halves: D[15:0]=bf16(lo), D[31:16]=bf16(hi).
__device__ __forceinline__ unsigned pk2(float lo, float hi) {
  union { float f; unsigned u; } a, b;
  a.f = lo; b.f = hi;
  return __builtin_amdgcn_perm(b.u + 0x8000u, a.u + 0x8000u, 0x07060302u);
}
__device__ __forceinline__ void unp4(ull v, float* d) {
  unsigned a = (unsigned)v, b = (unsigned)(v >> 32);
  union { unsigned u; float f; } x;
  x.u = a << 16;         d[0] = x.f;
  x.u = a & 0xffff0000u; d[1] = x.f;
  x.u = b << 16;         d[2] = x.f;
  x.u = b & 0xffff0000u; d[3] = x.f;
}
__device__ __forceinline__ bf16x8 mkfrag(unsigned w0, unsigned w1, unsigned w2, unsigned w3) {
  union { bf16x8 v; unsigned u[4]; } U;
  U.u[0] = w0; U.u[1] = w1; U.u[2] = w2; U.u[3] = w3;
  return U.v;
}
__device__ __forceinline__ f32x4 mfma16(bf16x8 a, bf16x8 b, f32x4 c) {
  return __builtin_amdgcn_mfma_f32_16x16x32_bf16(a, b, c, 0, 0, 0);
}

// ROUND-11 = ROUND-9 resubmitted (2x infra failure, no data): psi-16x16
// geometry (r8-verified correct) at launch_bounds(512,2) — r8 proved (512,4)
// spills catastrophically (FETCH 676MB/WRITE 1.4GB scratch). 256-reg budget,
// ~160 demand; spare registers spent on 2-way chunk unroll so two independent
// mm1->hop->mm2->hop->mm3 chains interleave and cover the dependency-latency
// stall that dominated r6 (310/498 us).
//   psi(16*mt + 4*g + r) = 32*(mt>>1) + 8*g + 4*(mt&1) + r
// applied to W1/W2 output columns and b2; hop is register-contiguous.
__global__ __launch_bounds__(512, 2) void rrsep(
    const float* __restrict__ y_real, const float* __restrict__ y_imag,
    const float* __restrict__ W1, const float* __restrict__ b1,
    const float* __restrict__ W2, const float* __restrict__ b2,
    const float* __restrict__ W3, const float* __restrict__ b3,
    float* __restrict__ out)
{
  __shared__ __align__(16) char smem[SMEM_BYTES];
  unsigned short* xs = (unsigned short*)(smem + X_OFF);
  unsigned short* os = (unsigned short*)(smem + O_OFF);
  unsigned short* ys = (unsigned short*)(smem + Y_OFF);
  float* es = (float*)(smem + E_OFF);

  const int tid  = (int)threadIdx.x;
  const int lane = tid & 63;
  const int w    = tid >> 6;     // wave 0..7
  const int p    = w >> 1;       // port
  const int c    = w & 1;        // channel
  const int q    = lane & 15;    // A/B row-col lane index
  const int g    = lane >> 4;    // k-group / C-row group
  const long r0  = (long)blockIdx.x * RT;

  // psi for A-frag rows (m' = 16mt + q) — stage-invariant
  int mpsi[4];
  #pragma unroll
  for (int mt = 0; mt < 4; ++mt)
    mpsi[mt] = 32*(mt>>1) + 8*(q>>2) + 4*(mt&1) + (q&3);

  // ---------------- prologue: coalesced load, normalize, init x ----------------
  {
    float* stg = (float*)smem;   // overlays x region before its first use
    if (tid < 384) {
      ((f32x4*)stg)[tid]          = ((const f32x4*)(y_real + r0 * 12))[tid];
      ((f32x4*)(stg + 1536))[tid] = ((const f32x4*)(y_imag + r0 * 12))[tid];
    }
    __syncthreads();
    float yv[24]; float ev = 0.f, inv = 0.f;
    if (tid < RT) {
      float acc = 0.f;
      #pragma unroll
      for (int l = 0; l < 12; ++l) {
        yv[l]      = stg[tid * 12 + l];
        yv[12 + l] = stg[1536 + tid * 12 + l];
        acc += yv[l] * yv[l] + yv[12 + l] * yv[12 + l];
      }
      ev  = sqrtf(acc * (1.f / 12.f));
      inv = 1.f / (ev + 1e-8f);
    }
    __syncthreads();   // all slab reads done before x overwrites the region
    if (tid < RT) {
      es[tid] = ev;
      unsigned pkw[12];
      #pragma unroll
      for (int j = 0; j < 12; ++j) pkw[j] = pk2(yv[2*j] * inv, yv[2*j+1] * inv);
      ull* yr0 = (ull*)(ys + (0 * RT + tid) * 12);
      yr0[0] = (ull)pkw[0] | ((ull)pkw[1] << 32);
      yr0[1] = (ull)pkw[2] | ((ull)pkw[3] << 32);
      yr0[2] = (ull)pkw[4] | ((ull)pkw[5] << 32);
      ull* yr1 = (ull*)(ys + (1 * RT + tid) * 12);
      yr1[0] = (ull)pkw[6]  | ((ull)pkw[7]  << 32);
      yr1[1] = (ull)pkw[8]  | ((ull)pkw[9]  << 32);
      yr1[2] = (ull)pkw[10] | ((ull)pkw[11] << 32);
      #pragma unroll
      for (int p2 = 0; p2 < 4; ++p2) {
        u32x4* xr = (u32x4*)(xs + (p2 * RT + tid) * XSTR);
        u32x4 t0; t0[0]=pkw[0]; t0[1]=pkw[1]; t0[2]=pkw[2]; t0[3]=pkw[3];
        u32x4 t1; t1[0]=pkw[4]; t1[1]=pkw[5]; t1[2]=pkw[6]; t1[3]=pkw[7];
        u32x4 t2; t2[0]=pkw[8]; t2[1]=pkw[9]; t2[2]=pkw[10]; t2[3]=pkw[11];
        u32x4 t3; t3[0]=pk2(1.f, 0.f); t3[1]=0u; t3[2]=0u; t3[3]=0u;  // aug x[24]=1, pad 25..31=0
        xr[0]=t0; xr[1]=t1; xr[2]=t2; xr[3]=t3;
      }
    }
    __syncthreads();
  }

  #pragma unroll 1
  for (int s = 0; s < 3; ++s) {
    const int pc = (s * 4 + p) * 2 + c;
    const float* W1g = W1 + pc * 24 * 64;
    const float* b1g = b1 + pc * 64;
    const float* W2g = W2 + pc * 64 * 64;
    const float* b2g = b2 + pc * 64;
    const float* W3g = W3 + pc * 64 * 12;
    const float* b3g = b3 + pc * 12;

    // ---- W1 A-frags (psi on output cols, b1 folded at k=24): elem j <-> k=8g+j ----
    bf16x8 w1f[4];
    #pragma unroll
    for (int mt = 0; mt < 4; ++mt) {
      unsigned u[4];
      #pragma unroll
      for (int wq = 0; wq < 4; ++wq) {
        int k0 = 8*g + 2*wq;
        float v0 = (k0 < 24) ? W1g[k0*64 + mpsi[mt]] : ((k0 == 24) ? b1g[mpsi[mt]] : 0.f);
        float v1 = (k0+1 < 24) ? W1g[(k0+1)*64 + mpsi[mt]] : 0.f;   // k0+1 odd, never 24
        u[wq] = pk2(v0, v1);
      }
      w1f[mt] = mkfrag(u[0], u[1], u[2], u[3]);
    }
    // ---- W2 A-frags (input k actual, psi on output cols): k = 32kt+8g+j ----
    bf16x8 w2f[2][4];
    #pragma unroll
    for (int kt = 0; kt < 2; ++kt)
      #pragma unroll
      for (int mt = 0; mt < 4; ++mt) {
        unsigned u[4];
        #pragma unroll
        for (int wq = 0; wq < 4; ++wq) {
          int k0 = 32*kt + 8*g + 2*wq;
          u[wq] = pk2(W2g[k0*64 + mpsi[mt]], W2g[(k0+1)*64 + mpsi[mt]]);
        }
        w2f[kt][mt] = mkfrag(u[0], u[1], u[2], u[3]);
      }
    // ---- W3 A-frags (all actual; M=12 padded to 16 with zeros) ----
    bf16x8 w3f[2];
    #pragma unroll
    for (int kt = 0; kt < 2; ++kt) {
      unsigned u[4];
      #pragma unroll
      for (int wq = 0; wq < 4; ++wq) {
        int k0 = 32*kt + 8*g + 2*wq;
        float v0 = (q < 12) ? W3g[k0*12 + q]     : 0.f;
        float v1 = (q < 12) ? W3g[(k0+1)*12 + q] : 0.f;
        u[wq] = pk2(v0, v1);
      }
      w3f[kt] = mkfrag(u[0], u[1], u[2], u[3]);
    }
    // ---- biases as C-init (round-1-verified): C row = 4g+reg ----
    f32x4 b2f[4], b3f;
    #pragma unroll
    for (int mt = 0; mt < 4; ++mt) {
      #pragma unroll
      for (int r = 0; r < 4; ++r)
        b2f[mt][r] = b2g[32*(mt>>1) + 8*g + 4*(mt&1) + r];   // b2[psi(16mt+4g+r)]
    }
    #pragma unroll
    for (int r = 0; r < 4; ++r) {
      int m = 4*g + r;
      b3f[r] = (m < 12) ? b3g[m] : 0.f;
    }

    // ---------------- main: 8 chunks of 16 rows; unroll 2 for chunk-level ILP ----------------
    #pragma unroll 2
    for (int ch = 0; ch < 8; ++ch) {
      const int row = ch * 16 + q;
      bf16x8 xb = *(const bf16x8*)(xs + (p * RT + row) * XSTR + 8 * g);

      // mm1: H1psi^T = W1psi^T · [X|1]^T   (K=32 covers 24 data + aug + pad)
      f32x4 c1[4];
      #pragma unroll
      for (int mt = 0; mt < 4; ++mt) c1[mt] = mfma16(w1f[mt], xb, f32x4{0.f,0.f,0.f,0.f});

      // hop1: relu+pack contiguous C-regs; fr1[kt] elem 4a+r = c1[2kt+a][r]
      bf16x8 fr1[2];
      #pragma unroll
      for (int kt = 0; kt < 2; ++kt)
        fr1[kt] = mkfrag(
          pk2(fmaxf(c1[2*kt][0], 0.f),   fmaxf(c1[2*kt][1], 0.f)),
          pk2(fmaxf(c1[2*kt][2], 0.f),   fmaxf(c1[2*kt][3], 0.f)),
          pk2(fmaxf(c1[2*kt+1][0], 0.f), fmaxf(c1[2*kt+1][1], 0.f)),
          pk2(fmaxf(c1[2*kt+1][2], 0.f), fmaxf(c1[2*kt+1][3], 0.f)));

      // mm2: bias via C-init, K=64 as two k-windows
      f32x4 c2[4];
      #pragma unroll
      for (int mt = 0; mt < 4; ++mt) {
        c2[mt] = mfma16(w2f[0][mt], fr1[0], b2f[mt]);
        c2[mt] = mfma16(w2f[1][mt], fr1[1], c2[mt]);
      }
      // hop2
      bf16x8 fr2[2];
      #pragma unroll
      for (int kt = 0; kt < 2; ++kt)
        fr2[kt] = mkfrag(
          pk2(fmaxf(c2[2*kt][0], 0.f),   fmaxf(c2[2*kt][1], 0.f)),
          pk2(fmaxf(c2[2*kt][2], 0.f),   fmaxf(c2[2*kt][3], 0.f)),
          pk2(fmaxf(c2[2*kt+1][0], 0.f), fmaxf(c2[2*kt+1][1], 0.f)),
          pk2(fmaxf(c2[2*kt+1][2], 0.f), fmaxf(c2[2*kt+1][3], 0.f)));

      // mm3: O^T (12 valid rows), bias via C-init
      f32x4 c3 = mfma16(w3f[0], fr2[0], b3f);
      c3 = mfma16(w3f[1], fr2[1], c3);

      // o-write: C reg r = out-feat 4g+r at data row `row`; g<3 covers feats 0..11
      if (g < 3) {
        unsigned k0 = pk2(c3[0], c3[1]);
        unsigned k1 = pk2(c3[2], c3[3]);
        *(ull*)(os + ((p * 2 + c) * 129 + row) * 12 + 4 * g) = (ull)k0 | ((ull)k1 << 32);
      }
    }
    __syncthreads();

    // ---------------- residual combine (round-3-verified, unchanged) ----------------
    {
      const int r = tid >> 2, pp = tid & 3;
      float sum[24], own[24], yn[24];
      #pragma unroll
      for (int k = 0; k < 24; ++k) sum[k] = 0.f;
      #pragma unroll
      for (int pp2 = 0; pp2 < 4; ++pp2)
        #pragma unroll
        for (int cc = 0; cc < 2; ++cc) {
          const ull* orow = (const ull*)(os + ((pp2 * 2 + cc) * 129 + r) * 12);
          float t[12];
          unp4(orow[0], t); unp4(orow[1], t + 4); unp4(orow[2], t + 8);
          #pragma unroll
          for (int l = 0; l < 12; ++l) sum[cc * 12 + l] += t[l];
        }
      #pragma unroll
      for (int cc = 0; cc < 2; ++cc) {
        const ull* orow = (const ull*)(os + ((pp * 2 + cc) * 129 + r) * 12);
        unp4(orow[0], own + cc * 12); unp4(orow[1], own + cc * 12 + 4); unp4(orow[2], own + cc * 12 + 8);
        const ull* yrow = (const ull*)(ys + (cc * RT + r) * 12);
        unp4(yrow[0], yn + cc * 12); unp4(yrow[1], yn + cc * 12 + 4); unp4(yrow[2], yn + cc * 12 + 8);
      }
      if (s < 2) {
        unsigned xw[12];
        #pragma unroll
        for (int j = 0; j < 12; ++j) {
          float v0 = own[2*j]   + (yn[2*j]   - sum[2*j]);
          float v1 = own[2*j+1] + (yn[2*j+1] - sum[2*j+1]);
          xw[j] = pk2(v0, v1);
        }
        u32x4* xr = (u32x4*)(xs + (pp * RT + r) * XSTR);
        u32x4 t0; t0[0]=xw[0]; t0[1]=xw[1]; t0[2]=xw[2];  t0[3]=xw[3];
        u32x4 t1; t1[0]=xw[4]; t1[1]=xw[5]; t1[2]=xw[6];  t1[3]=xw[7];
        u32x4 t2; t2[0]=xw[8]; t2[1]=xw[9]; t2[2]=xw[10]; t2[3]=xw[11];
        xr[0]=t0; xr[1]=t1; xr[2]=t2;
        __syncthreads();
      } else {
        const float ev = es[r];
        float vals[24];
        #pragma unroll
        for (int l = 0; l < 12; ++l) {
          vals[2*l]   = (own[l]      + yn[l]      - sum[l])      * ev;
          vals[2*l+1] = (own[12 + l] + yn[12 + l] - sum[12 + l]) * ev;
        }
        __syncthreads();                       // all o/y/e reads done
        float* vstg = (float*)smem;            // overlays x/o regions
        f32x4* vw = (f32x4*)(vstg + r * 96 + pp * 24);
        #pragma unroll
        for (int i = 0; i < 6; ++i) {
          f32x4 t; t[0]=vals[4*i]; t[1]=vals[4*i+1]; t[2]=vals[4*i+2]; t[3]=vals[4*i+3];
          vw[i] = t;
        }
        __syncthreads();
        const f32x4* vp = (const f32x4*)vstg;
        f32x4* og = (f32x4*)(out + r0 * 96);
        #pragma unroll
        for (int i = 0; i < 6; ++i) og[tid + 512 * i] = vp[tid + 512 * i];
      }
    }
  }
}

extern "C" void kernel_launch(void* const* d_in, const int* in_sizes, int n_in,
                              void* d_out, int out_size, void* d_ws, size_t ws_size,
                              hipStream_t stream) {
  const float* y_real = (const float*)d_in[0];
  const float* y_imag = (const float*)d_in[1];
  const float* W1 = (const float*)d_in[2];
  const float* b1 = (const float*)d_in[3];
  const float* W2 = (const float*)d_in[4];
  const float* b2 = (const float*)d_in[5];
  const float* W3 = (const float*)d_in[6];
  const float* b3 = (const float*)d_in[7];
  float* out = (float*)d_out;

  hipLaunchKernelGGL(rrsep, dim3(NB), dim3(512), 0, stream,
                     y_real, y_imag, W1, b1, W2, b2, W3, b3, out);
}